// Round 13
// baseline (67.961 us; speedup 1.0000x reference)
//
#include <hip/hip_runtime.h>
#include <cmath>

#define EPSBN 1e-5f

namespace {
constexpr int C_IN = 512;
constexpr int CC   = 64;
constexpr int CD   = 8;
constexpr int HW   = 256;
constexpr int DHW  = CD * HW;        // 2048
constexpr int QSZ  = 2 * CC * DHW;   // 262144 floats per q/k/v buffer

// padded input layout for conv: [n 2][dp 10][g 8][row 18][col 18][cil 8] bf16
constexpr int PG    = 18 * 18;           // 324
constexpr int GPLN  = PG * 8;            // 2592 elems per (dp,g) plane
constexpr int PADSZ = 2 * 10 * 8 * GPLN; // 414720 elems per branch
// Wt layout: [branch][chunk 96][tapk 9][coh 2][pg 64][ci8] bf16 where the
// 16B granule index pg = (2*co + ks) ^ (co & 7)  (bank-floor swizzle; the
// same XOR is applied on the LDS read side; DMA copies stay linear).
constexpr int WTSZ  = 27 * 512 * 64;     // 884736 elems per branch

typedef __attribute__((ext_vector_type(8))) short bf16x8;
typedef __attribute__((ext_vector_type(4))) float f32x4;
typedef __attribute__((ext_vector_type(16))) float f32x16;

typedef unsigned int u32_g __attribute__((address_space(1)));
typedef unsigned int u32_l __attribute__((address_space(3)));

__device__ inline unsigned short f2bf(float f) {
    unsigned u = __float_as_uint(f);
    return (unsigned short)((u + 0x7fffu + ((u >> 16) & 1u)) >> 16);
}
}

// ---------------------------------------------------------------------------
// head kernel (merged prep + qkv, one launch):
//   [0,256)     qkv MFMA GEMM (inline f32->bf16 weight conversion)
//   [256,661)   zero padded P/D buffers
//   [661,1685)  conv weight relayout+swizzle (coalesced source reads)
//   [1685,1689) BN coefficient precompute
// qkv blocks are placed FIRST so they get CUs immediately; prep blocks
// (pure memory) fill the remaining CUs concurrently.
// ---------------------------------------------------------------------------
__global__ __launch_bounds__(256) void head_kernel(
    const float* __restrict__ x,
    const float* __restrict__ Wq, const float* __restrict__ Wk,
    const float* __restrict__ Wv,
    const float* __restrict__ bq, const float* __restrict__ gq,
    const float* __restrict__ btq, const float* __restrict__ mq,
    const float* __restrict__ vq,
    const float* __restrict__ bk, const float* __restrict__ gk,
    const float* __restrict__ btk, const float* __restrict__ mk,
    const float* __restrict__ vk,
    const float* __restrict__ bv, const float* __restrict__ gv,
    const float* __restrict__ btv, const float* __restrict__ mv,
    const float* __restrict__ vv,
    const float* __restrict__ Ws, const float* __restrict__ Wd,
    const float* __restrict__ bs, const float* __restrict__ gs,
    const float* __restrict__ bts, const float* __restrict__ ms,
    const float* __restrict__ vs,
    const float* __restrict__ bd, const float* __restrict__ gd,
    const float* __restrict__ btd, const float* __restrict__ md,
    const float* __restrict__ vd,
    uint4* __restrict__ pads, unsigned short* __restrict__ Wt,
    float2* __restrict__ BNc,
    float* __restrict__ outq, float* __restrict__ outk, float* __restrict__ outv)
{
    int bid = blockIdx.x;
    int t = threadIdx.x;

    if (bid < 256) {
        // ---------------- qkv GEMM ----------------
        int n = bid >> 7, p0 = (bid & 127) * 16;

        __shared__ __align__(16) unsigned short xs[16 * 512];   // 16 KB

        const float* xb = x + ((size_t)n * C_IN) * DHW + p0;
#pragma unroll
        for (int pass = 0; pass < 8; ++pass) {
            int idx = pass * 256 + t;          // 0..2047
            int ci = idx >> 2, pq = idx & 3;
            float4 v4 = *reinterpret_cast<const float4*>(xb + (size_t)ci * DHW + pq * 4);
            float arr[4] = {v4.x, v4.y, v4.z, v4.w};
#pragma unroll
            for (int u = 0; u < 4; ++u) {
                int pos = pq * 4 + u;
                int boff = pos * 1024 + ((ci * 2) ^ ((pos & 7) << 4));
                *reinterpret_cast<unsigned short*>(
                    reinterpret_cast<char*>(xs) + boff) = f2bf(arr[u]);
            }
        }
        __syncthreads();

        int wid = t >> 6, lane = t & 63;
        int l15 = lane & 15, l4 = lane >> 4;
        int mh = wid * 3;
        int pos = l15;

        bf16x8 bfr[16];
        const char* xsb = reinterpret_cast<const char*>(xs) + pos * 1024;
        int swz = (pos & 7) << 4;
#pragma unroll
        for (int kk = 0; kk < 16; ++kk)
            bfr[kk] = *reinterpret_cast<const bf16x8*>(xsb + ((kk * 64 + l4 * 16) ^ swz));

        f32x4 acc[3];
#pragma unroll
        for (int i = 0; i < 3; ++i) acc[i] = (f32x4){0.f, 0.f, 0.f, 0.f};

#pragma unroll
        for (int i = 0; i < 3; ++i) {
            int mf = mh + i;
            int br = mf >> 2;
            const float* Wsel = br == 0 ? Wq : br == 1 ? Wk : Wv;
            int c = (mf & 3) * 16 + l15;
            const float* wr = Wsel + (size_t)c * 512 + l4 * 8;
#pragma unroll
            for (int kk = 0; kk < 16; ++kk) {
                float4 wa = *reinterpret_cast<const float4*>(wr + kk * 32);
                float4 wb = *reinterpret_cast<const float4*>(wr + kk * 32 + 4);
                bf16x8 af;
                af[0] = (short)f2bf(wa.x); af[1] = (short)f2bf(wa.y);
                af[2] = (short)f2bf(wa.z); af[3] = (short)f2bf(wa.w);
                af[4] = (short)f2bf(wb.x); af[5] = (short)f2bf(wb.y);
                af[6] = (short)f2bf(wb.z); af[7] = (short)f2bf(wb.w);
                acc[i] = __builtin_amdgcn_mfma_f32_16x16x32_bf16(af, bfr[kk], acc[i], 0, 0, 0);
            }
        }

#pragma unroll
        for (int i = 0; i < 3; ++i) {
            int mf = mh + i;
            int br = mf >> 2;
            const float* bb  = br == 0 ? bq  : br == 1 ? bk  : bv;
            const float* gg  = br == 0 ? gq  : br == 1 ? gk  : gv;
            const float* bt  = br == 0 ? btq : br == 1 ? btk : btv;
            const float* mm  = br == 0 ? mq  : br == 1 ? mk  : mv;
            const float* vvp = br == 0 ? vq  : br == 1 ? vk  : vv;
            float*       op  = br == 0 ? outq : br == 1 ? outk : outv;
            int cb = (mf & 3) * 16 + l4 * 4;
#pragma unroll
            for (int r = 0; r < 4; ++r) {
                int c = cb + r;
                float s = gg[c] * rsqrtf(vvp[c] + EPSBN);
                float val = (acc[i][r] + bb[c] - mm[c]) * s + bt[c];
                op[((size_t)(n * CC + c)) * DHW + p0 + pos] = fmaxf(val, 0.f);
            }
        }
    } else if (bid < 661) {
        // ---------------- zero pads ----------------
        pads[(bid - 256) * 256 + t] = make_uint4(0, 0, 0, 0);
    } else if (bid < 1685) {
        // ---------------- conv weight relayout ----------------
        int b2 = bid - 661;
        int b  = b2 >> 9;
        int co = b2 & 511;
        const float* W = b ? Wd : Ws;
        int cog = co >> 6, co_l = co & 63;
        int r  = co_l & 31, hi = co_l >> 5;
        unsigned short* o = Wt + (size_t)b * WTSZ;
        for (int k2 = t; k2 < 27 * 64; k2 += 256) {
            int ci  = k2 / 27;              // contiguous source reads
            int tap = k2 - ci * 27;
            int kd = tap / 9, tapk = tap - kd * 9;
            int half = ci >> 5, cl = ci & 31;
            int cig = cl >> 4, ci16 = cl & 15;
            int ks = ci16 >> 3;
            float w = W[(size_t)co * 1728 + k2];
            int chunk = ((cog * 2 + half) * 3 + kd) * 2 + cig;
            int pg = (r * 2 + ks) ^ (r & 7);                 // bank swizzle
            o[(size_t)chunk * 9216 + tapk * 1024 + hi * 512
              + pg * 8 + (ci16 & 7)] = f2bf(w);
        }
    } else {
        // ---------------- BN coefficients ----------------
        int gid = (bid - 1685) * 256 + t;     // 0..1023
        if (gid < 1024) {
            int br = gid >> 9, co = gid & 511;
            float s, o;
            if (br == 0) {
                s = gs[co] * rsqrtf(vs[co] + EPSBN);
                o = (bs[co] - ms[co]) * s + bts[co];
            } else {
                s = gd[co] * rsqrtf(vd[co] + EPSBN);
                o = (bd[co] - md[co]) * s + btd[co];
            }
            BNc[gid] = make_float2(s, o);
        }
    }
}

// ---------------------------------------------------------------------------
// attention (merged): blocks [0,1024) = spatial patt; [1024,1152) = datt.
// ---------------------------------------------------------------------------
__global__ __launch_bounds__(256) void att_kernel(
    const float* __restrict__ q, const float* __restrict__ k,
    const float* __restrict__ v,
    unsigned short* __restrict__ Pp, unsigned short* __restrict__ Dp)
{
    __shared__ float sk[256], sq[256], sw[256], red[4];
    int t = threadIdx.x;
    int bid = blockIdx.x;

    if (bid < 1024) {
        int n = bid >> 9, c = (bid >> 3) & 63, d = bid & 7;
        size_t base = (size_t)bid * HW;
        float kt = k[base + t];
        float qt = q[base + t];
        float vt = v[base + t];
        sk[t] = kt;
        sq[t] = qt;

        float m = kt;
#pragma unroll
        for (int off = 32; off >= 1; off >>= 1)
            m = fmaxf(m, __shfl_xor(m, off));
        if ((t & 63) == 0) red[t >> 6] = m;
        __syncthreads();
        float kmax = fmaxf(fmaxf(red[0], red[1]), fmaxf(red[2], red[3]));

        float qkm = qt * kmax;
        float d0 = 0.f, d1 = 0.f, d2 = 0.f, d3 = 0.f;
        for (int j = 0; j < 256; j += 4) {
            d0 += __expf(fmaf(qt, sk[j + 0], -qkm));
            d1 += __expf(fmaf(qt, sk[j + 1], -qkm));
            d2 += __expf(fmaf(qt, sk[j + 2], -qkm));
            d3 += __expf(fmaf(qt, sk[j + 3], -qkm));
        }
        float den = (d0 + d1) + (d2 + d3);
        sw[t] = vt / den;
        __syncthreads();

        float kjm = kt - kmax;
        float o0 = 0.f, o1 = 0.f, o2 = 0.f, o3 = 0.f;
        for (int i = 0; i < 256; i += 4) {
            o0 += sw[i + 0] * __expf(sq[i + 0] * kjm);
            o1 += sw[i + 1] * __expf(sq[i + 1] * kjm);
            o2 += sw[i + 2] * __expf(sq[i + 2] * kjm);
            o3 += sw[i + 3] * __expf(sq[i + 3] * kjm);
        }
        float o = (o0 + o1) + (o2 + o3);

        int h = t >> 4, w = t & 15;
        size_t dst = ((((size_t)(n * 10 + d + 1) * 8 + (c >> 3)) * PG)
                      + (h + 1) * 18 + (w + 1)) * 8 + (c & 7);
        Pp[dst] = f2bf(o);
    } else {
        int g = (bid - 1024) * 256 + t;
        int nc = g >> 8, hw = g & 255;
        int n = nc >> 6, c = nc & 63;
        size_t base = (size_t)nc * DHW + hw;

        float qv[8], kv[8], vv_[8];
#pragma unroll
        for (int d = 0; d < 8; ++d) {
            qv[d]  = q[base + d * HW];
            kv[d]  = k[base + d * HW];
            vv_[d] = v[base + d * HW];
        }
        float kmax = 0.f;
#pragma unroll
        for (int d = 0; d < 8; ++d) kmax = fmaxf(kmax, kv[d]);

        float wgt[8];
#pragma unroll
        for (int i = 0; i < 8; ++i) {
            float den = 0.f, qkm = qv[i] * kmax;
#pragma unroll
            for (int j = 0; j < 8; ++j)
                den += __expf(fmaf(qv[i], kv[j], -qkm));
            wgt[i] = vv_[i] / den;
        }
        int h = hw >> 4, w = hw & 15;
#pragma unroll
        for (int j = 0; j < 8; ++j) {
            float o = 0.f, kjm = kv[j] - kmax;
#pragma unroll
            for (int i = 0; i < 8; ++i)
                o += wgt[i] * __expf(qv[i] * kjm);
            size_t dst = ((((size_t)(n * 10 + j + 1) * 8 + (c >> 3)) * PG)
                          + (h + 1) * 18 + (w + 1)) * 8 + (c & 7);
            Dp[dst] = f2bf(o);
        }
    }
}

// ---------------------------------------------------------------------------
// fused dual-branch conv, 32x32x16 MFMA = R10 structure (bulk input staging,
// measured fastest) + counted-vmcnt weight pipeline (T4).
// grid = 256 = (cog 8 = XCD) x (pgb 2) x (sl 16); block 256 thr = 4 waves =
// (ph 2 pos-halves) x (br 2). Wave: 64 co x 64 pos, acc = 2x2 f32x16.
// Per step: barrier_A -> DMAW(c+1) (9 loads/wave) -> s_waitcnt vmcnt(9)
// (chunk c landed, c+1 stays IN FLIGHT) -> barrier_B -> COMPUTE(c).
// Inputs staged in bulk (ISTAGE half 0 / half 1); step-6 vmcnt(9)
// transitively proves ISTAGE(1) complete.
// ---------------------------------------------------------------------------
__global__ __launch_bounds__(256, 1) void conv_fused_kernel(
    const unsigned short* __restrict__ Pp, const unsigned short* __restrict__ Dp,
    const unsigned short* __restrict__ Wt,
    const float2* __restrict__ BNc,
    const float* __restrict__ x, const float* __restrict__ gama,
    float* __restrict__ out)
{
    int bid = blockIdx.x;
    int cog = bid & 7;             // == XCD (round-robin) -> weights L2-local
    int pgb = (bid >> 3) & 1;
    int sl  = bid >> 4;
    int n = sl >> 3, d = sl & 7;

    __shared__ __align__(16) unsigned short lds_in[24 * 1536];    // 73728 B
    __shared__ __align__(16) unsigned short lds_w[2 * 18432];     // 73728 B

    int t = threadIdx.x;
    int wid = t >> 6, lane = t & 63;
    int ph = wid & 1, br = wid >> 1;
    int col  = lane & 31;          // pos / co within 32-tile
    int wcol = lane & 15;
    int hl   = (lane >> 4) & 1;
    int ks   = lane >> 5;          // ci granule within ci16
    int gA   = ((col * 2 + ks) ^ (col & 7)) * 8;  // swizzled A granule offset

    f32x16 acc[2][2];
#pragma unroll
    for (int m = 0; m < 2; ++m)
#pragma unroll
        for (int p = 0; p < 2; ++p)
#pragma unroll
            for (int r = 0; r < 16; ++r)
                acc[m][p][r] = 0.f;

// bulk input stage for one ci-half: 24 pieces (2 br x 12 planes) x 3 DMA,
// distributed so each wave issues exactly 18 instructions. Window = rows
// [pgb*8, pgb*8+10); the third DMA over-reads 192 B (stays inside ws) into
// the never-read LDS tail.
#define ISTAGE(hf_) do {                                                      \
    _Pragma("unroll")                                                         \
    for (int pc = 0; pc < 24; ++pc) {                                         \
        const unsigned short* sb = ((pc >= 12) ? Dp : Pp)                     \
            + ((size_t)((n * 10 + d + ((pc % 12) >> 2)) * 8 + (hf_) * 4       \
                        + ((pc % 12) & 3))) * GPLN + pgb * 1152;              \
        _Pragma("unroll")                                                     \
        for (int j = 0; j < 3; ++j) {                                         \
            if (((pc * 3 + j) & 3) == wid)                                    \
                __builtin_amdgcn_global_load_lds(                             \
                    (const u32_g*)(sb + j * 512 + lane * 8),                  \
                    (u32_l*)(lds_in + pc * 1536 + j * 512), 16, 0, 0);        \
        }                                                                     \
    }                                                                         \
} while (0)

// weight chunk DMA: exactly 9 instructions per wave.
#define DMAW(c_) do {                                                         \
    const int ch_ = (((cog * 2 + ((c_) / 6)) * 3 + (((c_) % 6) >> 1)) * 2     \
                     + ((c_) & 1)) * 9216;                                    \
    _Pragma("unroll")                                                         \
    for (int j = 0; j < 9; ++j) {                                             \
        int base = j * 2048 + wid * 512;                                      \
        const unsigned short* s0 = (base < 9216)                              \
            ? (Wt + ch_ + base)                                               \
            : (Wt + WTSZ + ch_ + (base - 9216));                              \
        __builtin_amdgcn_global_load_lds(                                     \
            (const u32_g*)(s0 + lane * 8),                                    \
            (u32_l*)(lds_w + ((c_) & 1) * 18432 + base), 16, 0, 0);           \
    }                                                                         \
} while (0)

#define COMPUTE(c_) do {                                                      \
    const int kd_ = ((c_) % 6) >> 1, cig_ = (c_) & 1;                         \
    const unsigned short* wb_ = lds_w + ((c_) & 1) * 18432 + br * 9216;       \
    const unsigned short* bp_ = lds_in + br * (12 * 1536)                     \
                                + (kd_ * 4 + cig_ * 2 + ks) * 1536;           \
    _Pragma("unroll")                                                         \
    for (int tapk = 0; tapk < 9; ++tapk) {                                    \
        const int kh_ = tapk / 3, kw_ = tapk % 3;                             \
        bf16x8 a0 = *(const bf16x8*)(wb_ + tapk * 1024 + gA);                 \
        bf16x8 a1 = *(const bf16x8*)(wb_ + tapk * 1024 + 512 + gA);           \
        bf16x8 b0 = *(const bf16x8*)(bp_ + ((ph * 4 + hl + kh_) * 18          \
                                     + wcol + kw_) * 8);                      \
        bf16x8 b1 = *(const bf16x8*)(bp_ + ((ph * 4 + 2 + hl + kh_) * 18      \
                                     + wcol + kw_) * 8);                      \
        acc[0][0] = __builtin_amdgcn_mfma_f32_32x32x16_bf16(a0, b0,           \
                        acc[0][0], 0, 0, 0);                                  \
        acc[0][1] = __builtin_amdgcn_mfma_f32_32x32x16_bf16(a0, b1,           \
                        acc[0][1], 0, 0, 0);                                  \
        acc[1][0] = __builtin_amdgcn_mfma_f32_32x32x16_bf16(a1, b0,           \
                        acc[1][0], 0, 0, 0);                                  \
        acc[1][1] = __builtin_amdgcn_mfma_f32_32x32x16_bf16(a1, b1,           \
                        acc[1][1], 0, 0, 0);                                  \
    }                                                                         \
} while (0)

    ISTAGE(0);
    DMAW(0);

#pragma unroll
    for (int c = 0; c < 12; ++c) {
        if (c > 0)
            __builtin_amdgcn_s_barrier();      // A: COMPUTE(c-1) done block-wide
        if (c < 11) {
            DMAW(c + 1);                       // 9 loads -> buffer (c+1)&1
            asm volatile("s_waitcnt vmcnt(9)" ::: "memory");   // chunk c ready
        } else {
            asm volatile("s_waitcnt vmcnt(0)" ::: "memory");
        }
        __builtin_amdgcn_s_barrier();          // B: ready block-wide
        COMPUTE(c);
        if (c == 5) {
            __builtin_amdgcn_s_barrier();      // all waves done with half-0 input
            ISTAGE(1);                         // lands before step-6's vmcnt(9)
        }
    }

#undef ISTAGE
#undef DMAW
#undef COMPUTE

    // ---- fused epilogue: S-waves -> LDS, D-waves combine + store ----
    // (ep region = lds_w buffer 0 bytes [0,32K); COMPUTE(11) read buffer 1)
    float gm = gama[0];
    float* ep = reinterpret_cast<float*>(lds_w);

    if (br == 0) {
#pragma unroll
        for (int m = 0; m < 2; ++m)
#pragma unroll
            for (int p = 0; p < 2; ++p)
#pragma unroll
                for (int r = 0; r < 16; ++r) {
                    int row = (r & 3) + 8 * (r >> 2) + 4 * ks;
                    float2 c2 = BNc[cog * 64 + m * 32 + row];
                    float v = fmaxf(acc[m][p][r] * c2.x + c2.y, 0.f);
                    ep[ph * 4096 + (m * 32 + row) * 64 + p * 32 + col] = v;
                }
    }
    __syncthreads();
    if (br == 1) {
#pragma unroll
        for (int m = 0; m < 2; ++m)
#pragma unroll
            for (int p = 0; p < 2; ++p)
#pragma unroll
                for (int r = 0; r < 16; ++r) {
                    int row = (r & 3) + 8 * (r >> 2) + 4 * ks;
                    int co = cog * 64 + m * 32 + row;
                    float2 c2 = BNc[512 + co];
                    float rd = fmaxf(acc[m][p][r] * c2.x + c2.y, 0.f);
                    float rp = ep[ph * 4096 + (m * 32 + row) * 64 + p * 32 + col];
                    int pos = pgb * 128 + ph * 64 + p * 32 + col;
                    size_t oi = ((size_t)(n * 512 + co)) * 2048 + d * 256 + pos;
                    out[oi] = gm * (rp + rd) + x[oi];
                }
    }
}

// ---------------------------------------------------------------------------
extern "C" void kernel_launch(void* const* d_in, const int* in_sizes, int n_in,
                              void* d_out, int out_size, void* d_ws, size_t ws_size,
                              hipStream_t stream)
{
    const float* x    = (const float*)d_in[0];
    const float* gama = (const float*)d_in[1];
    const float* Wq  = (const float*)d_in[2];
    const float* bq  = (const float*)d_in[3];
    const float* gq  = (const float*)d_in[4];
    const float* btq = (const float*)d_in[5];
    const float* mq  = (const float*)d_in[6];
    const float* vq  = (const float*)d_in[7];
    const float* Wk  = (const float*)d_in[8];
    const float* bk  = (const float*)d_in[9];
    const float* gk  = (const float*)d_in[10];
    const float* btk = (const float*)d_in[11];
    const float* mk  = (const float*)d_in[12];
    const float* vk  = (const float*)d_in[13];
    const float* Wv  = (const float*)d_in[14];
    const float* bv  = (const float*)d_in[15];
    const float* gv  = (const float*)d_in[16];
    const float* btv = (const float*)d_in[17];
    const float* mv  = (const float*)d_in[18];
    const float* vv  = (const float*)d_in[19];
    const float* Ws  = (const float*)d_in[20];
    const float* bs  = (const float*)d_in[21];
    const float* gs  = (const float*)d_in[22];
    const float* bts = (const float*)d_in[23];
    const float* ms  = (const float*)d_in[24];
    const float* vs  = (const float*)d_in[25];
    const float* Wd  = (const float*)d_in[26];
    const float* bd  = (const float*)d_in[27];
    const float* gd  = (const float*)d_in[28];
    const float* btd = (const float*)d_in[29];
    const float* md  = (const float*)d_in[30];
    const float* vd  = (const float*)d_in[31];

    char* ws = (char*)d_ws;
    unsigned short* Pp   = (unsigned short*)ws;                 // 829440 B
    unsigned short* Dp   = Pp + PADSZ;                          // 829440 B
    unsigned short* Wt   = Dp + PADSZ;                          // 3538944 B
    float* q = (float*)(ws + 5394432);
    float* k = q + QSZ;
    float* v = k + QSZ;
    float2* BNc = (float2*)(ws + 5394432 + 3 * 1048576);        // 8192 B

    head_kernel<<<1689, 256, 0, stream>>>(
        x,
        Wq, Wk, Wv,
        bq, gq, btq, mq, vq,
        bk, gk, btk, mk, vk,
        bv, gv, btv, mv, vv,
        Ws, Wd,
        bs, gs, bts, ms, vs,
        bd, gd, btd, md, vd,
        (uint4*)Pp, Wt, BNc,
        q, k, v);

    att_kernel<<<1152, 256, 0, stream>>>(q, k, v, Pp, Dp);

    conv_fused_kernel<<<256, 256, 0, stream>>>(
        Pp, Dp, Wt, BNc,
        x, gama, (float*)d_out);
}

// Round 14
// 67.253 us; speedup vs baseline: 1.0105x; 1.0105x over previous
//
#include <hip/hip_runtime.h>
#include <cmath>

#define EPSBN 1e-5f

namespace {
constexpr int C_IN = 512;
constexpr int CC   = 64;
constexpr int CD   = 8;
constexpr int HW   = 256;
constexpr int DHW  = CD * HW;        // 2048
constexpr int QSZ  = 2 * CC * DHW;   // 262144 floats per q/k/v buffer

// padded input layout for conv: [n 2][dp 10][g 8][row 18][col 18][cil 8] bf16
constexpr int PG    = 18 * 18;           // 324
constexpr int GPLN  = PG * 8;            // 2592 elems per (dp,g) plane
constexpr int PADSZ = 2 * 10 * 8 * GPLN; // 414720 elems per branch
// Wt layout: [branch][chunk 96][tapk 9][coh 2][pg 64][ci8] bf16 where the
// 16B granule index pg = (2*co + ks) ^ (co & 7)  (bank-floor swizzle; the
// same XOR is applied on the LDS read side; DMA copies stay linear).
constexpr int WTSZ  = 27 * 512 * 64;     // 884736 elems per branch

typedef __attribute__((ext_vector_type(8))) short bf16x8;
typedef __attribute__((ext_vector_type(4))) float f32x4;
typedef __attribute__((ext_vector_type(16))) float f32x16;

typedef unsigned int u32_g __attribute__((address_space(1)));
typedef unsigned int u32_l __attribute__((address_space(3)));

__device__ inline unsigned short f2bf(float f) {
    unsigned u = __float_as_uint(f);
    return (unsigned short)((u + 0x7fffu + ((u >> 16) & 1u)) >> 16);
}
}

// ---------------------------------------------------------------------------
// prep: [0,405) zero pads | [405,1429) weight relayout+swizzle (coalesced
// source reads) | [1429,1621) Wqkv | [1621,1625) BN coefficients
// ---------------------------------------------------------------------------
__global__ __launch_bounds__(256) void prep_kernel(
    const float* __restrict__ Ws, const float* __restrict__ Wd,
    const float* __restrict__ Wq, const float* __restrict__ Wk,
    const float* __restrict__ Wv,
    const float* __restrict__ bs, const float* __restrict__ gs,
    const float* __restrict__ bts, const float* __restrict__ ms,
    const float* __restrict__ vs,
    const float* __restrict__ bd, const float* __restrict__ gd,
    const float* __restrict__ btd, const float* __restrict__ md,
    const float* __restrict__ vd,
    uint4* __restrict__ pads, unsigned short* __restrict__ Wt,
    unsigned short* __restrict__ Wqkv, float2* __restrict__ BNc)
{
    int bid = blockIdx.x;
    int t = threadIdx.x;
    if (bid < 405) {
        pads[bid * 256 + t] = make_uint4(0, 0, 0, 0);
    } else if (bid < 1429) {
        int b2 = bid - 405;
        int b  = b2 >> 9;
        int co = b2 & 511;
        const float* W = b ? Wd : Ws;
        int cog = co >> 6, co_l = co & 63;
        int r  = co_l & 31, hi = co_l >> 5;
        unsigned short* o = Wt + (size_t)b * WTSZ;
        for (int k2 = t; k2 < 27 * 64; k2 += 256) {
            int ci  = k2 / 27;              // contiguous source reads
            int tap = k2 - ci * 27;
            int kd = tap / 9, tapk = tap - kd * 9;
            int half = ci >> 5, cl = ci & 31;
            int cig = cl >> 4, ci16 = cl & 15;
            int ks = ci16 >> 3;
            float w = W[(size_t)co * 1728 + k2];
            int chunk = ((cog * 2 + half) * 3 + kd) * 2 + cig;
            int pg = (r * 2 + ks) ^ (r & 7);                 // bank swizzle
            o[(size_t)chunk * 9216 + tapk * 1024 + hi * 512
              + pg * 8 + (ci16 & 7)] = f2bf(w);
        }
    } else if (bid < 1621) {
        int co = bid - 1429;          // 0..191
        const float* W = co < 64 ? Wq : co < 128 ? Wk : Wv;
        int c = co & 63;
        for (int ci = t; ci < 512; ci += 256)
            Wqkv[(size_t)co * 512 + ci] = f2bf(W[(size_t)c * 512 + ci]);
    } else {
        int gid = (bid - 1621) * 256 + t;     // 0..1023
        if (gid < 1024) {
            int br = gid >> 9, co = gid & 511;
            float s, o;
            if (br == 0) {
                s = gs[co] * rsqrtf(vs[co] + EPSBN);
                o = (bs[co] - ms[co]) * s + bts[co];
            } else {
                s = gd[co] * rsqrtf(vd[co] + EPSBN);
                o = (bd[co] - md[co]) * s + btd[co];
            }
            BNc[gid] = make_float2(s, o);
        }
    }
}

// ---------------------------------------------------------------------------
// fused transpose + MFMA GEMM for q/k/v (+BN+ReLU). (unchanged, R10 form)
// ---------------------------------------------------------------------------
__global__ __launch_bounds__(256) void qkv_gemm_kernel(
    const float* __restrict__ x, const unsigned short* __restrict__ Wqkv,
    const float* __restrict__ bq, const float* __restrict__ gq,
    const float* __restrict__ btq, const float* __restrict__ mq,
    const float* __restrict__ vq,
    const float* __restrict__ bk, const float* __restrict__ gk,
    const float* __restrict__ btk, const float* __restrict__ mk,
    const float* __restrict__ vk,
    const float* __restrict__ bv, const float* __restrict__ gv,
    const float* __restrict__ btv, const float* __restrict__ mv,
    const float* __restrict__ vv,
    float* __restrict__ outq, float* __restrict__ outk, float* __restrict__ outv)
{
    int bid = blockIdx.x;
    int n = bid >> 7, p0 = (bid & 127) * 16;

    __shared__ __align__(16) unsigned short xs[16 * 512];   // 16 KB
    int t = threadIdx.x;

    const float* xb = x + ((size_t)n * C_IN) * DHW + p0;
#pragma unroll
    for (int pass = 0; pass < 8; ++pass) {
        int idx = pass * 256 + t;          // 0..2047
        int ci = idx >> 2, pq = idx & 3;
        float4 v4 = *reinterpret_cast<const float4*>(xb + (size_t)ci * DHW + pq * 4);
        float arr[4] = {v4.x, v4.y, v4.z, v4.w};
#pragma unroll
        for (int u = 0; u < 4; ++u) {
            int pos = pq * 4 + u;
            int boff = pos * 1024 + ((ci * 2) ^ ((pos & 7) << 4));
            *reinterpret_cast<unsigned short*>(
                reinterpret_cast<char*>(xs) + boff) = f2bf(arr[u]);
        }
    }
    __syncthreads();

    int wid = t >> 6, lane = t & 63;
    int l15 = lane & 15, l4 = lane >> 4;
    int mh = wid * 3;
    int pos = l15;

    bf16x8 bfr[16];
    const char* xsb = reinterpret_cast<const char*>(xs) + pos * 1024;
    int swz = (pos & 7) << 4;
#pragma unroll
    for (int kk = 0; kk < 16; ++kk)
        bfr[kk] = *reinterpret_cast<const bf16x8*>(xsb + ((kk * 64 + l4 * 16) ^ swz));

    f32x4 acc[3];
#pragma unroll
    for (int i = 0; i < 3; ++i) acc[i] = (f32x4){0.f, 0.f, 0.f, 0.f};

#pragma unroll
    for (int i = 0; i < 3; ++i) {
        const unsigned short* wrow =
            Wqkv + ((size_t)(mh + i) * 16 + l15) * 512 + l4 * 8;
#pragma unroll
        for (int kk = 0; kk < 16; ++kk) {
            bf16x8 af = *reinterpret_cast<const bf16x8*>(wrow + kk * 32);
            acc[i] = __builtin_amdgcn_mfma_f32_16x16x32_bf16(af, bfr[kk], acc[i], 0, 0, 0);
        }
    }

#pragma unroll
    for (int i = 0; i < 3; ++i) {
        int mf = mh + i;
        int br = mf >> 2;
        const float* bb  = br == 0 ? bq  : br == 1 ? bk  : bv;
        const float* gg  = br == 0 ? gq  : br == 1 ? gk  : gv;
        const float* bt  = br == 0 ? btq : br == 1 ? btk : btv;
        const float* mm  = br == 0 ? mq  : br == 1 ? mk  : mv;
        const float* vvp = br == 0 ? vq  : br == 1 ? vk  : vv;
        float*       op  = br == 0 ? outq : br == 1 ? outk : outv;
        int cb = (mf & 3) * 16 + l4 * 4;
#pragma unroll
        for (int r = 0; r < 4; ++r) {
            int c = cb + r;
            float s = gg[c] * rsqrtf(vvp[c] + EPSBN);
            float val = (acc[i][r] + bb[c] - mm[c]) * s + bt[c];
            op[((size_t)(n * CC + c)) * DHW + p0 + pos] = fmaxf(val, 0.f);
        }
    }
}

// ---------------------------------------------------------------------------
// attention (merged): blocks [0,1024) = spatial patt; [1024,1152) = datt.
// (unchanged, R10 form)
// ---------------------------------------------------------------------------
__global__ __launch_bounds__(256) void att_kernel(
    const float* __restrict__ q, const float* __restrict__ k,
    const float* __restrict__ v,
    unsigned short* __restrict__ Pp, unsigned short* __restrict__ Dp)
{
    __shared__ float sk[256], sq[256], sw[256], red[4];
    int t = threadIdx.x;
    int bid = blockIdx.x;

    if (bid < 1024) {
        int n = bid >> 9, c = (bid >> 3) & 63, d = bid & 7;
        size_t base = (size_t)bid * HW;
        float kt = k[base + t];
        float qt = q[base + t];
        float vt = v[base + t];
        sk[t] = kt;
        sq[t] = qt;

        float m = kt;
#pragma unroll
        for (int off = 32; off >= 1; off >>= 1)
            m = fmaxf(m, __shfl_xor(m, off));
        if ((t & 63) == 0) red[t >> 6] = m;
        __syncthreads();
        float kmax = fmaxf(fmaxf(red[0], red[1]), fmaxf(red[2], red[3]));

        float qkm = qt * kmax;
        float d0 = 0.f, d1 = 0.f, d2 = 0.f, d3 = 0.f;
        for (int j = 0; j < 256; j += 4) {
            d0 += __expf(fmaf(qt, sk[j + 0], -qkm));
            d1 += __expf(fmaf(qt, sk[j + 1], -qkm));
            d2 += __expf(fmaf(qt, sk[j + 2], -qkm));
            d3 += __expf(fmaf(qt, sk[j + 3], -qkm));
        }
        float den = (d0 + d1) + (d2 + d3);
        sw[t] = vt / den;
        __syncthreads();

        float kjm = kt - kmax;
        float o0 = 0.f, o1 = 0.f, o2 = 0.f, o3 = 0.f;
        for (int i = 0; i < 256; i += 4) {
            o0 += sw[i + 0] * __expf(sq[i + 0] * kjm);
            o1 += sw[i + 1] * __expf(sq[i + 1] * kjm);
            o2 += sw[i + 2] * __expf(sq[i + 2] * kjm);
            o3 += sw[i + 3] * __expf(sq[i + 3] * kjm);
        }
        float o = (o0 + o1) + (o2 + o3);

        int h = t >> 4, w = t & 15;
        size_t dst = ((((size_t)(n * 10 + d + 1) * 8 + (c >> 3)) * PG)
                      + (h + 1) * 18 + (w + 1)) * 8 + (c & 7);
        Pp[dst] = f2bf(o);
    } else {
        int g = (bid - 1024) * 256 + t;
        int nc = g >> 8, hw = g & 255;
        int n = nc >> 6, c = nc & 63;
        size_t base = (size_t)nc * DHW + hw;

        float qv[8], kv[8], vv_[8];
#pragma unroll
        for (int d = 0; d < 8; ++d) {
            qv[d]  = q[base + d * HW];
            kv[d]  = k[base + d * HW];
            vv_[d] = v[base + d * HW];
        }
        float kmax = 0.f;
#pragma unroll
        for (int d = 0; d < 8; ++d) kmax = fmaxf(kmax, kv[d]);

        float wgt[8];
#pragma unroll
        for (int i = 0; i < 8; ++i) {
            float den = 0.f, qkm = qv[i] * kmax;
#pragma unroll
            for (int j = 0; j < 8; ++j)
                den += __expf(fmaf(qv[i], kv[j], -qkm));
            wgt[i] = vv_[i] / den;
        }
        int h = hw >> 4, w = hw & 15;
#pragma unroll
        for (int j = 0; j < 8; ++j) {
            float o = 0.f, kjm = kv[j] - kmax;
#pragma unroll
            for (int i = 0; i < 8; ++i)
                o += wgt[i] * __expf(qv[i] * kjm);
            size_t dst = ((((size_t)(n * 10 + j + 1) * 8 + (c >> 3)) * PG)
                          + (h + 1) * 18 + (w + 1)) * 8 + (c & 7);
            Dp[dst] = f2bf(o);
        }
    }
}

// ---------------------------------------------------------------------------
// fused dual-branch conv, 32x32x16 MFMA — R10 structure, now 512 threads =
// 8 waves = 2 waves/SIMD (the single change this round).
// grid = 256 = (cog 8 = XCD) x (pgb 2) x (sl 16). Wave = 64 co x 32 pos,
// 8 waves = (posq 4) x (br 2); acc = 2 x f32x16 (32 VGPR).
// Bulk input staging (ISTAGE half 0/1) + per-chunk weight double buffer,
// __syncthreads drains (R10's measured-best discipline).
// ---------------------------------------------------------------------------
__global__ __launch_bounds__(512, 1) void conv_fused_kernel(
    const unsigned short* __restrict__ Pp, const unsigned short* __restrict__ Dp,
    const unsigned short* __restrict__ Wt,
    const float2* __restrict__ BNc,
    const float* __restrict__ x, const float* __restrict__ gama,
    float* __restrict__ out)
{
    int bid = blockIdx.x;
    int cog = bid & 7;             // == XCD (round-robin) -> weights L2-local
    int pgb = (bid >> 3) & 1;
    int sl  = bid >> 4;
    int n = sl >> 3, d = sl & 7;

    __shared__ __align__(16) unsigned short lds_in[24 * 1536];    // 73728 B
    __shared__ __align__(16) unsigned short lds_w[2 * 18432];     // 73728 B

    int t = threadIdx.x;
    int wid = t >> 6, lane = t & 63;
    int posq = wid & 3, br = wid >> 2;
    int col  = lane & 31;          // pos / co within 32-tile
    int wcol = lane & 15;
    int hl   = (lane >> 4) & 1;
    int ks   = lane >> 5;          // ci granule within ci16
    int gA   = ((col * 2 + ks) ^ (col & 7)) * 8;  // swizzled A granule offset

    f32x16 acc[2];
#pragma unroll
    for (int m = 0; m < 2; ++m)
#pragma unroll
        for (int r = 0; r < 16; ++r)
            acc[m][r] = 0.f;

// bulk input stage for one ci-half: 24 pieces (2 br x 12 planes) x 3 DMA =
// 72 instructions distributed so each of the 8 waves issues exactly 9.
// Window = rows [pgb*8, pgb*8+10); the third DMA over-reads 192 B (stays
// inside ws) into the never-read LDS tail.
#define ISTAGE(hf_) do {                                                      \
    _Pragma("unroll")                                                         \
    for (int pc = 0; pc < 24; ++pc) {                                         \
        const unsigned short* sb = ((pc >= 12) ? Dp : Pp)                     \
            + ((size_t)((n * 10 + d + ((pc % 12) >> 2)) * 8 + (hf_) * 4       \
                        + ((pc % 12) & 3))) * GPLN + pgb * 1152;              \
        _Pragma("unroll")                                                     \
        for (int j = 0; j < 3; ++j) {                                         \
            if (((pc * 3 + j) & 7) == wid)                                    \
                __builtin_amdgcn_global_load_lds(                             \
                    (const u32_g*)(sb + j * 512 + lane * 8),                  \
                    (u32_l*)(lds_in + pc * 1536 + j * 512), 16, 0, 0);        \
        }                                                                     \
    }                                                                         \
} while (0)

// weight chunk DMA: 36 x 1KB segments over 8 waves (waves 0-3: 5, 4-7: 4).
#define DMAW(c_) do {                                                         \
    const int ch_ = (((cog * 2 + ((c_) / 6)) * 3 + (((c_) % 6) >> 1)) * 2     \
                     + ((c_) & 1)) * 9216;                                    \
    _Pragma("unroll")                                                         \
    for (int j = 0; j < 5; ++j) {                                             \
        int base = j * 4096 + wid * 512;                                      \
        if (base < 18432) {                                                   \
            const unsigned short* s0 = (base < 9216)                          \
                ? (Wt + ch_ + base)                                           \
                : (Wt + WTSZ + ch_ + (base - 9216));                          \
            __builtin_amdgcn_global_load_lds(                                 \
                (const u32_g*)(s0 + lane * 8),                                \
                (u32_l*)(lds_w + ((c_) & 1) * 18432 + base), 16, 0, 0);       \
        }                                                                     \
    }                                                                         \
} while (0)

#define COMPUTE(c_) do {                                                      \
    const int kd_ = ((c_) % 6) >> 1, cig_ = (c_) & 1;                         \
    const unsigned short* wb_ = lds_w + ((c_) & 1) * 18432 + br * 9216;       \
    const unsigned short* bp_ = lds_in + br * (12 * 1536)                     \
                                + (kd_ * 4 + cig_ * 2 + ks) * 1536;           \
    _Pragma("unroll")                                                         \
    for (int tapk = 0; tapk < 9; ++tapk) {                                    \
        const int kh_ = tapk / 3, kw_ = tapk % 3;                             \
        bf16x8 a0 = *(const bf16x8*)(wb_ + tapk * 1024 + gA);                 \
        bf16x8 a1 = *(const bf16x8*)(wb_ + tapk * 1024 + 512 + gA);           \
        bf16x8 b0 = *(const bf16x8*)(bp_ + ((posq * 2 + hl + kh_) * 18        \
                                     + wcol + kw_) * 8);                      \
        acc[0] = __builtin_amdgcn_mfma_f32_32x32x16_bf16(a0, b0,              \
                     acc[0], 0, 0, 0);                                        \
        acc[1] = __builtin_amdgcn_mfma_f32_32x32x16_bf16(a1, b0,              \
                     acc[1], 0, 0, 0);                                        \
    }                                                                         \
} while (0)

    ISTAGE(0);
    DMAW(0);
    __syncthreads();

#pragma unroll
    for (int c = 0; c < 12; ++c) {
        if (c < 11) DMAW(c + 1);       // next chunk flies over COMPUTE(c)
        COMPUTE(c);
        __syncthreads();               // drains gload_lds queue
        if (c == 5) {                  // switch to ci-half 1
            ISTAGE(1);
            __syncthreads();
        }
    }

#undef ISTAGE
#undef DMAW
#undef COMPUTE

    // ---- fused epilogue: S-waves -> LDS, D-waves combine + store ----
    // (ep = lds_w shorts [0,16384) = buffer 0; COMPUTE(11) read buffer 1)
    float gm = gama[0];
    float* ep = reinterpret_cast<float*>(lds_w);

    if (br == 0) {
#pragma unroll
        for (int m = 0; m < 2; ++m)
#pragma unroll
            for (int r = 0; r < 16; ++r) {
                int row = (r & 3) + 8 * (r >> 2) + 4 * ks;
                float2 c2 = BNc[cog * 64 + m * 32 + row];
                float v = fmaxf(acc[m][r] * c2.x + c2.y, 0.f);
                ep[posq * 2048 + (m * 32 + row) * 32 + col] = v;
            }
    }
    __syncthreads();
    if (br == 1) {
#pragma unroll
        for (int m = 0; m < 2; ++m)
#pragma unroll
            for (int r = 0; r < 16; ++r) {
                int row = (r & 3) + 8 * (r >> 2) + 4 * ks;
                int co = cog * 64 + m * 32 + row;
                float2 c2 = BNc[512 + co];
                float rd = fmaxf(acc[m][r] * c2.x + c2.y, 0.f);
                float rp = ep[posq * 2048 + (m * 32 + row) * 32 + col];
                int pos = pgb * 128 + posq * 32 + col;
                size_t oi = ((size_t)(n * 512 + co)) * 2048 + d * 256 + pos;
                out[oi] = gm * (rp + rd) + x[oi];
            }
    }
}

// ---------------------------------------------------------------------------
extern "C" void kernel_launch(void* const* d_in, const int* in_sizes, int n_in,
                              void* d_out, int out_size, void* d_ws, size_t ws_size,
                              hipStream_t stream)
{
    const float* x    = (const float*)d_in[0];
    const float* gama = (const float*)d_in[1];
    const float* Wq  = (const float*)d_in[2];
    const float* bq  = (const float*)d_in[3];
    const float* gq  = (const float*)d_in[4];
    const float* btq = (const float*)d_in[5];
    const float* mq  = (const float*)d_in[6];
    const float* vq  = (const float*)d_in[7];
    const float* Wk  = (const float*)d_in[8];
    const float* bk  = (const float*)d_in[9];
    const float* gk  = (const float*)d_in[10];
    const float* btk = (const float*)d_in[11];
    const float* mk  = (const float*)d_in[12];
    const float* vk  = (const float*)d_in[13];
    const float* Wv  = (const float*)d_in[14];
    const float* bv  = (const float*)d_in[15];
    const float* gv  = (const float*)d_in[16];
    const float* btv = (const float*)d_in[17];
    const float* mv  = (const float*)d_in[18];
    const float* vv  = (const float*)d_in[19];
    const float* Ws  = (const float*)d_in[20];
    const float* bs  = (const float*)d_in[21];
    const float* gs  = (const float*)d_in[22];
    const float* bts = (const float*)d_in[23];
    const float* ms  = (const float*)d_in[24];
    const float* vs  = (const float*)d_in[25];
    const float* Wd  = (const float*)d_in[26];
    const float* bd  = (const float*)d_in[27];
    const float* gd  = (const float*)d_in[28];
    const float* btd = (const float*)d_in[29];
    const float* md  = (const float*)d_in[30];
    const float* vd  = (const float*)d_in[31];

    char* ws = (char*)d_ws;
    unsigned short* Pp   = (unsigned short*)ws;                 // 829440 B
    unsigned short* Dp   = Pp + PADSZ;                          // 829440 B
    unsigned short* Wt   = Dp + PADSZ;                          // 3538944 B
    unsigned short* Wqkv = Wt + 2 * WTSZ;                       // 196608 B
    float* q = (float*)(ws + 5394432);
    float* k = q + QSZ;
    float* v = k + QSZ;
    float2* BNc = (float2*)(ws + 5394432 + 3 * 1048576);        // 8192 B

    prep_kernel<<<1625, 256, 0, stream>>>(
        Ws, Wd, Wq, Wk, Wv,
        bs, gs, bts, ms, vs,
        bd, gd, btd, md, vd,
        (uint4*)Pp, Wt, Wqkv, BNc);

    qkv_gemm_kernel<<<256, 256, 0, stream>>>(
        x, Wqkv,
        bq, gq, btq, mq, vq,
        bk, gk, btk, mk, vk,
        bv, gv, btv, mv, vv,
        q, k, v);

    att_kernel<<<1152, 256, 0, stream>>>(q, k, v, Pp, Dp);

    conv_fused_kernel<<<256, 512, 0, stream>>>(
        Pp, Dp, Wt, BNc,
        x, gama, (float*)d_out);
}

// Round 16
// 66.110 us; speedup vs baseline: 1.0280x; 1.0173x over previous
//
#include <hip/hip_runtime.h>
#include <cmath>

#define EPSBN 1e-5f

namespace {
constexpr int C_IN = 512;
constexpr int CC   = 64;
constexpr int CD   = 8;
constexpr int HW   = 256;
constexpr int DHW  = CD * HW;        // 2048
constexpr int QSZ  = 2 * CC * DHW;   // 262144 floats per q/k/v buffer

// padded input layout for conv: [n 2][dp 10][g 8][row 18][col 18][cil 8] bf16
constexpr int PG    = 18 * 18;           // 324
constexpr int GPLN  = PG * 8;            // 2592 elems per (dp,g) plane
constexpr int PADSZ = 2 * 10 * 8 * GPLN; // 414720 elems per branch
// Wt layout: [branch][chunk 96][tapk 9][coh 2][pg 64][ci8] bf16 where the
// 16B granule index pg = (2*co + ks) ^ (co & 7)  (bank-floor swizzle; the
// same XOR is applied on the LDS read side; DMA copies stay linear).
constexpr int WTSZ  = 27 * 512 * 64;     // 884736 elems per branch
constexpr float LOG2E = 1.44269504088896f;

typedef __attribute__((ext_vector_type(8))) short bf16x8;
typedef __attribute__((ext_vector_type(4))) float f32x4;
typedef __attribute__((ext_vector_type(16))) float f32x16;

typedef unsigned int u32_g __attribute__((address_space(1)));
typedef unsigned int u32_l __attribute__((address_space(3)));

__device__ inline unsigned short f2bf(float f) {
    unsigned u = __float_as_uint(f);
    return (unsigned short)((u + 0x7fffu + ((u >> 16) & 1u)) >> 16);
}
}

// ---------------------------------------------------------------------------
// prep_small: [0,192) Wqkv bf16 stack | [192,597) zero padded P/D buffers.
// Pads MUST be zeroed before att writes interior values (two launches later)
// — R15 raced by putting the zeroing in the att grid itself.
// ---------------------------------------------------------------------------
__global__ __launch_bounds__(256) void prep_small_kernel(
    const float* __restrict__ Wq, const float* __restrict__ Wk,
    const float* __restrict__ Wv, unsigned short* __restrict__ Wqkv,
    uint4* __restrict__ pads)
{
    int bid = blockIdx.x;
    int t = threadIdx.x;
    if (bid < 192) {
        int co = bid;                 // 0..191
        const float* W = co < 64 ? Wq : co < 128 ? Wk : Wv;
        int c = co & 63;
        for (int ci = t; ci < 512; ci += 256)
            Wqkv[(size_t)co * 512 + ci] = f2bf(W[(size_t)c * 512 + ci]);
    } else {
        pads[(bid - 192) * 256 + t] = make_uint4(0, 0, 0, 0);
    }
}

// ---------------------------------------------------------------------------
// fused transpose + MFMA GEMM for q/k/v (+BN+ReLU). (R10 exact)
// ---------------------------------------------------------------------------
__global__ __launch_bounds__(256) void qkv_gemm_kernel(
    const float* __restrict__ x, const unsigned short* __restrict__ Wqkv,
    const float* __restrict__ bq, const float* __restrict__ gq,
    const float* __restrict__ btq, const float* __restrict__ mq,
    const float* __restrict__ vq,
    const float* __restrict__ bk, const float* __restrict__ gk,
    const float* __restrict__ btk, const float* __restrict__ mk,
    const float* __restrict__ vk,
    const float* __restrict__ bv, const float* __restrict__ gv,
    const float* __restrict__ btv, const float* __restrict__ mv,
    const float* __restrict__ vv,
    float* __restrict__ outq, float* __restrict__ outk, float* __restrict__ outv)
{
    int bid = blockIdx.x;
    int n = bid >> 7, p0 = (bid & 127) * 16;

    __shared__ __align__(16) unsigned short xs[16 * 512];   // 16 KB
    int t = threadIdx.x;

    const float* xb = x + ((size_t)n * C_IN) * DHW + p0;
#pragma unroll
    for (int pass = 0; pass < 8; ++pass) {
        int idx = pass * 256 + t;          // 0..2047
        int ci = idx >> 2, pq = idx & 3;
        float4 v4 = *reinterpret_cast<const float4*>(xb + (size_t)ci * DHW + pq * 4);
        float arr[4] = {v4.x, v4.y, v4.z, v4.w};
#pragma unroll
        for (int u = 0; u < 4; ++u) {
            int pos = pq * 4 + u;
            int boff = pos * 1024 + ((ci * 2) ^ ((pos & 7) << 4));
            *reinterpret_cast<unsigned short*>(
                reinterpret_cast<char*>(xs) + boff) = f2bf(arr[u]);
        }
    }
    __syncthreads();

    int wid = t >> 6, lane = t & 63;
    int l15 = lane & 15, l4 = lane >> 4;
    int mh = wid * 3;
    int pos = l15;

    bf16x8 bfr[16];
    const char* xsb = reinterpret_cast<const char*>(xs) + pos * 1024;
    int swz = (pos & 7) << 4;
#pragma unroll
    for (int kk = 0; kk < 16; ++kk)
        bfr[kk] = *reinterpret_cast<const bf16x8*>(xsb + ((kk * 64 + l4 * 16) ^ swz));

    f32x4 acc[3];
#pragma unroll
    for (int i = 0; i < 3; ++i) acc[i] = (f32x4){0.f, 0.f, 0.f, 0.f};

#pragma unroll
    for (int i = 0; i < 3; ++i) {
        const unsigned short* wrow =
            Wqkv + ((size_t)(mh + i) * 16 + l15) * 512 + l4 * 8;
#pragma unroll
        for (int kk = 0; kk < 16; ++kk) {
            bf16x8 af = *reinterpret_cast<const bf16x8*>(wrow + kk * 32);
            acc[i] = __builtin_amdgcn_mfma_f32_16x16x32_bf16(af, bfr[kk], acc[i], 0, 0, 0);
        }
    }

#pragma unroll
    for (int i = 0; i < 3; ++i) {
        int mf = mh + i;
        int br = mf >> 2;
        const float* bb  = br == 0 ? bq  : br == 1 ? bk  : bv;
        const float* gg  = br == 0 ? gq  : br == 1 ? gk  : gv;
        const float* bt  = br == 0 ? btq : br == 1 ? btk : btv;
        const float* mm  = br == 0 ? mq  : br == 1 ? mk  : mv;
        const float* vvp = br == 0 ? vq  : br == 1 ? vk  : vv;
        float*       op  = br == 0 ? outq : br == 1 ? outk : outv;
        int cb = (mf & 3) * 16 + l4 * 4;
#pragma unroll
        for (int r = 0; r < 4; ++r) {
            int c = cb + r;
            float s = gg[c] * rsqrtf(vvp[c] + EPSBN);
            float val = (acc[i][r] + bb[c] - mm[c]) * s + bt[c];
            op[((size_t)(n * CC + c)) * DHW + p0 + pos] = fmaxf(val, 0.f);
        }
    }
}

// ---------------------------------------------------------------------------
// att + conv-prep (merged grid — WRITE-DISJOINT tail only):
//   [0,1024)     spatial patt (float4 LDS reads, exp2 pre-scale)
//   [1024,1152)  temporal datt
//   [1152,2176)  conv weight relayout+swizzle (writes Wt only)
//   [2176,2180)  BN coefficient precompute (writes BNc only)
// Wt/BNc are read only by the NEXT launch (conv), so no intra-grid ordering
// is assumed. (Pads zeroing moved to prep_small — R15's race.)
// ---------------------------------------------------------------------------
__global__ __launch_bounds__(256) void att_kernel(
    const float* __restrict__ q, const float* __restrict__ k,
    const float* __restrict__ v,
    const float* __restrict__ Ws, const float* __restrict__ Wd,
    const float* __restrict__ bs, const float* __restrict__ gs,
    const float* __restrict__ bts, const float* __restrict__ ms,
    const float* __restrict__ vs,
    const float* __restrict__ bd, const float* __restrict__ gd,
    const float* __restrict__ btd, const float* __restrict__ md,
    const float* __restrict__ vd,
    unsigned short* __restrict__ Pp, unsigned short* __restrict__ Dp,
    unsigned short* __restrict__ Wt, float2* __restrict__ BNc)
{
    __shared__ __align__(16) float sk[256], sq2[256], sw[256];
    __shared__ float red[4];
    int t = threadIdx.x;
    int bid = blockIdx.x;

    if (bid < 1024) {
        // ---- spatial attention over HW=256 for slice (n,c,d) ----
        int n = bid >> 9, c = (bid >> 3) & 63, d = bid & 7;
        size_t base = (size_t)bid * HW;
        float kt = k[base + t];
        float qt = q[base + t];
        float vt = v[base + t];
        float qt2 = qt * LOG2E;
        sk[t]  = kt;
        sq2[t] = qt2;

        float m = kt;
#pragma unroll
        for (int off = 32; off >= 1; off >>= 1)
            m = fmaxf(m, __shfl_xor(m, off));
        if ((t & 63) == 0) red[t >> 6] = m;
        __syncthreads();
        float kmax = fmaxf(fmaxf(red[0], red[1]), fmaxf(red[2], red[3]));

        float qkm2 = qt2 * kmax;
        float d0 = 0.f, d1 = 0.f, d2 = 0.f, d3 = 0.f;
        const float4* sk4 = reinterpret_cast<const float4*>(sk);
#pragma unroll 8
        for (int j = 0; j < 64; ++j) {
            float4 kk = sk4[j];
            d0 += __builtin_amdgcn_exp2f(fmaf(qt2, kk.x, -qkm2));
            d1 += __builtin_amdgcn_exp2f(fmaf(qt2, kk.y, -qkm2));
            d2 += __builtin_amdgcn_exp2f(fmaf(qt2, kk.z, -qkm2));
            d3 += __builtin_amdgcn_exp2f(fmaf(qt2, kk.w, -qkm2));
        }
        float den = (d0 + d1) + (d2 + d3);
        sw[t] = vt / den;
        __syncthreads();

        float kjm = kt - kmax;
        float o0 = 0.f, o1 = 0.f, o2 = 0.f, o3 = 0.f;
        const float4* sw4 = reinterpret_cast<const float4*>(sw);
        const float4* sq4 = reinterpret_cast<const float4*>(sq2);
#pragma unroll 8
        for (int i = 0; i < 64; ++i) {
            float4 ww = sw4[i];
            float4 qq = sq4[i];
            o0 += ww.x * __builtin_amdgcn_exp2f(qq.x * kjm);
            o1 += ww.y * __builtin_amdgcn_exp2f(qq.y * kjm);
            o2 += ww.z * __builtin_amdgcn_exp2f(qq.z * kjm);
            o3 += ww.w * __builtin_amdgcn_exp2f(qq.w * kjm);
        }
        float o = (o0 + o1) + (o2 + o3);

        int h = t >> 4, w = t & 15;
        size_t dst = ((((size_t)(n * 10 + d + 1) * 8 + (c >> 3)) * PG)
                      + (h + 1) * 18 + (w + 1)) * 8 + (c & 7);
        Pp[dst] = f2bf(o);
    } else if (bid < 1152) {
        // ---- temporal attention over D=8 per (n,c,h,w) ----
        int g = (bid - 1024) * 256 + t;
        int nc = g >> 8, hw = g & 255;
        int n = nc >> 6, c = nc & 63;
        size_t base = (size_t)nc * DHW + hw;

        float qv[8], kv[8], vv_[8];
#pragma unroll
        for (int d = 0; d < 8; ++d) {
            qv[d]  = q[base + d * HW];
            kv[d]  = k[base + d * HW];
            vv_[d] = v[base + d * HW];
        }
        float kmax = 0.f;
#pragma unroll
        for (int d = 0; d < 8; ++d) kmax = fmaxf(kmax, kv[d]);

        float wgt[8];
#pragma unroll
        for (int i = 0; i < 8; ++i) {
            float den = 0.f, qkm = qv[i] * kmax;
#pragma unroll
            for (int j = 0; j < 8; ++j)
                den += __expf(fmaf(qv[i], kv[j], -qkm));
            wgt[i] = vv_[i] / den;
        }
        int h = hw >> 4, w = hw & 15;
#pragma unroll
        for (int j = 0; j < 8; ++j) {
            float o = 0.f, kjm = kv[j] - kmax;
#pragma unroll
            for (int i = 0; i < 8; ++i)
                o += wgt[i] * __expf(qv[i] * kjm);
            size_t dst = ((((size_t)(n * 10 + j + 1) * 8 + (c >> 3)) * PG)
                          + (h + 1) * 18 + (w + 1)) * 8 + (c & 7);
            Dp[dst] = f2bf(o);
        }
    } else if (bid < 2176) {
        // ---- conv weight relayout+swizzle (coalesced source reads) ----
        int b2 = bid - 1152;
        int b  = b2 >> 9;
        int co = b2 & 511;
        const float* W = b ? Wd : Ws;
        int cog = co >> 6, co_l = co & 63;
        int r  = co_l & 31, hi = co_l >> 5;
        unsigned short* o = Wt + (size_t)b * WTSZ;
        for (int k2 = t; k2 < 27 * 64; k2 += 256) {
            int ci  = k2 / 27;
            int tap = k2 - ci * 27;
            int kd = tap / 9, tapk = tap - kd * 9;
            int half = ci >> 5, cl = ci & 31;
            int cig = cl >> 4, ci16 = cl & 15;
            int ks = ci16 >> 3;
            float w = W[(size_t)co * 1728 + k2];
            int chunk = ((cog * 2 + half) * 3 + kd) * 2 + cig;
            int pg = (r * 2 + ks) ^ (r & 7);                 // bank swizzle
            o[(size_t)chunk * 9216 + tapk * 1024 + hi * 512
              + pg * 8 + (ci16 & 7)] = f2bf(w);
        }
    } else {
        // ---- BN coefficients ----
        int gid = (bid - 2176) * 256 + t;     // 0..1023
        if (gid < 1024) {
            int br = gid >> 9, co = gid & 511;
            float s, o;
            if (br == 0) {
                s = gs[co] * rsqrtf(vs[co] + EPSBN);
                o = (bs[co] - ms[co]) * s + bts[co];
            } else {
                s = gd[co] * rsqrtf(vd[co] + EPSBN);
                o = (bd[co] - md[co]) * s + btd[co];
            }
            BNc[gid] = make_float2(s, o);
        }
    }
}

// ---------------------------------------------------------------------------
// fused dual-branch conv, 32x32x16 MFMA. (R10 exact — best measured)
// grid = 256 = (cog 8 = XCD) x (pgb 2) x (sl 16); block 256 thr = 4 waves =
// (ph 2 pos-halves) x (br 2). Wave: 64 co x 64 pos, acc = 2x2 f32x16.
// ALL staging via global_load_lds; bulk input slab + weight double buffer.
// ---------------------------------------------------------------------------
__global__ __launch_bounds__(256, 1) void conv_fused_kernel(
    const unsigned short* __restrict__ Pp, const unsigned short* __restrict__ Dp,
    const unsigned short* __restrict__ Wt,
    const float2* __restrict__ BNc,
    const float* __restrict__ x, const float* __restrict__ gama,
    float* __restrict__ out)
{
    int bid = blockIdx.x;
    int cog = bid & 7;             // == XCD (round-robin) -> weights L2-local
    int pgb = (bid >> 3) & 1;
    int sl  = bid >> 4;
    int n = sl >> 3, d = sl & 7;

    __shared__ __align__(16) unsigned short lds_in[24 * 1536];    // 73728 B
    __shared__ __align__(16) unsigned short lds_w[2 * 18432];     // 73728 B

    int t = threadIdx.x;
    int wid = t >> 6, lane = t & 63;
    int ph = wid & 1, br = wid >> 1;
    int col  = lane & 31;
    int wcol = lane & 15;
    int hl   = (lane >> 4) & 1;
    int ks   = lane >> 5;
    int gA   = ((col * 2 + ks) ^ (col & 7)) * 8;  // swizzled A granule offset

    f32x16 acc[2][2];
#pragma unroll
    for (int m = 0; m < 2; ++m)
#pragma unroll
        for (int p = 0; p < 2; ++p)
#pragma unroll
            for (int r = 0; r < 16; ++r)
                acc[m][p][r] = 0.f;

#define ISTAGE(hf_) do {                                                      \
    _Pragma("unroll")                                                         \
    for (int pc = 0; pc < 24; ++pc) {                                         \
        const unsigned short* sb = ((pc >= 12) ? Dp : Pp)                     \
            + ((size_t)((n * 10 + d + ((pc % 12) >> 2)) * 8 + (hf_) * 4       \
                        + ((pc % 12) & 3))) * GPLN + pgb * 1152;              \
        _Pragma("unroll")                                                     \
        for (int j = 0; j < 3; ++j) {                                         \
            if (((pc * 3 + j) & 3) == wid)                                    \
                __builtin_amdgcn_global_load_lds(                             \
                    (const u32_g*)(sb + j * 512 + lane * 8),                  \
                    (u32_l*)(lds_in + pc * 1536 + j * 512), 16, 0, 0);        \
        }                                                                     \
    }                                                                         \
} while (0)

#define DMAW(c_) do {                                                         \
    const int ch_ = (((cog * 2 + ((c_) / 6)) * 3 + (((c_) % 6) >> 1)) * 2     \
                     + ((c_) & 1)) * 9216;                                    \
    _Pragma("unroll")                                                         \
    for (int j = 0; j < 9; ++j) {                                             \
        int base = j * 2048 + wid * 512;                                      \
        const unsigned short* s0 = (base < 9216)                              \
            ? (Wt + ch_ + base)                                               \
            : (Wt + WTSZ + ch_ + (base - 9216));                              \
        __builtin_amdgcn_global_load_lds(                                     \
            (const u32_g*)(s0 + lane * 8),                                    \
            (u32_l*)(lds_w + ((c_) & 1) * 18432 + base), 16, 0, 0);           \
    }                                                                         \
} while (0)

#define COMPUTE(c_) do {                                                      \
    const int kd_ = ((c_) % 6) >> 1, cig_ = (c_) & 1;                         \
    const unsigned short* wb_ = lds_w + ((c_) & 1) * 18432 + br * 9216;       \
    const unsigned short* bp_ = lds_in + br * (12 * 1536)                     \
                                + (kd_ * 4 + cig_ * 2 + ks) * 1536;           \
    _Pragma("unroll")                                                         \
    for (int tapk = 0; tapk < 9; ++tapk) {                                    \
        const int kh_ = tapk / 3, kw_ = tapk % 3;                             \
        bf16x8 a0 = *(const bf16x8*)(wb_ + tapk * 1024 + gA);                 \
        bf16x8 a1 = *(const bf16x8*)(wb_ + tapk * 1024 + 512 + gA);           \
        bf16x8 b0 = *(const bf16x8*)(bp_ + ((ph * 4 + hl + kh_) * 18          \
                                     + wcol + kw_) * 8);                      \
        bf16x8 b1 = *(const bf16x8*)(bp_ + ((ph * 4 + 2 + hl + kh_) * 18      \
                                     + wcol + kw_) * 8);                      \
        acc[0][0] = __builtin_amdgcn_mfma_f32_32x32x16_bf16(a0, b0,           \
                        acc[0][0], 0, 0, 0);                                  \
        acc[0][1] = __builtin_amdgcn_mfma_f32_32x32x16_bf16(a0, b1,           \
                        acc[0][1], 0, 0, 0);                                  \
        acc[1][0] = __builtin_amdgcn_mfma_f32_32x32x16_bf16(a1, b0,           \
                        acc[1][0], 0, 0, 0);                                  \
        acc[1][1] = __builtin_amdgcn_mfma_f32_32x32x16_bf16(a1, b1,           \
                        acc[1][1], 0, 0, 0);                                  \
    }                                                                         \
} while (0)

    ISTAGE(0);
    DMAW(0);
    __syncthreads();

#pragma unroll
    for (int c = 0; c < 12; ++c) {
        if (c < 11) DMAW(c + 1);       // next chunk flies over COMPUTE(c)
        COMPUTE(c);
        __syncthreads();               // drains gload_lds queue
        if (c == 5) {                  // switch to ci-half 1
            ISTAGE(1);
            __syncthreads();
        }
    }

#undef ISTAGE
#undef DMAW
#undef COMPUTE

    // ---- fused epilogue: S-waves -> LDS, D-waves combine + store ----
    float gm = gama[0];
    float* ep = reinterpret_cast<float*>(lds_w);

    if (br == 0) {
#pragma unroll
        for (int m = 0; m < 2; ++m)
#pragma unroll
            for (int p = 0; p < 2; ++p)
#pragma unroll
                for (int r = 0; r < 16; ++r) {
                    int row = (r & 3) + 8 * (r >> 2) + 4 * ks;
                    float2 c2 = BNc[cog * 64 + m * 32 + row];
                    float v = fmaxf(acc[m][p][r] * c2.x + c2.y, 0.f);
                    ep[ph * 4096 + (m * 32 + row) * 64 + p * 32 + col] = v;
                }
    }
    __syncthreads();
    if (br == 1) {
#pragma unroll
        for (int m = 0; m < 2; ++m)
#pragma unroll
            for (int p = 0; p < 2; ++p)
#pragma unroll
                for (int r = 0; r < 16; ++r) {
                    int row = (r & 3) + 8 * (r >> 2) + 4 * ks;
                    int co = cog * 64 + m * 32 + row;
                    float2 c2 = BNc[512 + co];
                    float rd = fmaxf(acc[m][p][r] * c2.x + c2.y, 0.f);
                    float rp = ep[ph * 4096 + (m * 32 + row) * 64 + p * 32 + col];
                    int pos = pgb * 128 + ph * 64 + p * 32 + col;
                    size_t oi = ((size_t)(n * 512 + co)) * 2048 + d * 256 + pos;
                    out[oi] = gm * (rp + rd) + x[oi];
                }
    }
}

// ---------------------------------------------------------------------------
extern "C" void kernel_launch(void* const* d_in, const int* in_sizes, int n_in,
                              void* d_out, int out_size, void* d_ws, size_t ws_size,
                              hipStream_t stream)
{
    const float* x    = (const float*)d_in[0];
    const float* gama = (const float*)d_in[1];
    const float* Wq  = (const float*)d_in[2];
    const float* bq  = (const float*)d_in[3];
    const float* gq  = (const float*)d_in[4];
    const float* btq = (const float*)d_in[5];
    const float* mq  = (const float*)d_in[6];
    const float* vq  = (const float*)d_in[7];
    const float* Wk  = (const float*)d_in[8];
    const float* bk  = (const float*)d_in[9];
    const float* gk  = (const float*)d_in[10];
    const float* btk = (const float*)d_in[11];
    const float* mk  = (const float*)d_in[12];
    const float* vk  = (const float*)d_in[13];
    const float* Wv  = (const float*)d_in[14];
    const float* bv  = (const float*)d_in[15];
    const float* gv  = (const float*)d_in[16];
    const float* btv = (const float*)d_in[17];
    const float* mv  = (const float*)d_in[18];
    const float* vv  = (const float*)d_in[19];
    const float* Ws  = (const float*)d_in[20];
    const float* bs  = (const float*)d_in[21];
    const float* gs  = (const float*)d_in[22];
    const float* bts = (const float*)d_in[23];
    const float* ms  = (const float*)d_in[24];
    const float* vs  = (const float*)d_in[25];
    const float* Wd  = (const float*)d_in[26];
    const float* bd  = (const float*)d_in[27];
    const float* gd  = (const float*)d_in[28];
    const float* btd = (const float*)d_in[29];
    const float* md  = (const float*)d_in[30];
    const float* vd  = (const float*)d_in[31];

    char* ws = (char*)d_ws;
    unsigned short* Pp   = (unsigned short*)ws;                 // 829440 B
    unsigned short* Dp   = Pp + PADSZ;                          // 829440 B
    unsigned short* Wt   = Dp + PADSZ;                          // 3538944 B
    unsigned short* Wqkv = Wt + 2 * WTSZ;                       // 196608 B
    float* q = (float*)(ws + 5394432);
    float* k = q + QSZ;
    float* v = k + QSZ;
    float2* BNc = (float2*)(ws + 5394432 + 3 * 1048576);        // 8192 B

    prep_small_kernel<<<597, 256, 0, stream>>>(Wq, Wk, Wv, Wqkv, (uint4*)Pp);

    qkv_gemm_kernel<<<256, 256, 0, stream>>>(
        x, Wqkv,
        bq, gq, btq, mq, vq,
        bk, gk, btk, mk, vk,
        bv, gv, btv, mv, vv,
        q, k, v);

    att_kernel<<<2180, 256, 0, stream>>>(
        q, k, v,
        Ws, Wd,
        bs, gs, bts, ms, vs,
        bd, gd, btd, md, vd,
        Pp, Dp, Wt, BNc);

    conv_fused_kernel<<<256, 256, 0, stream>>>(
        Pp, Dp, Wt, BNc,
        x, gama, (float*)d_out);
}

// Round 18
// 59.752 us; speedup vs baseline: 1.1374x; 1.1064x over previous
//
#include <hip/hip_runtime.h>
#include <cmath>

#define EPSBN 1e-5f

namespace {
constexpr int C_IN = 512;
constexpr int CC   = 64;
constexpr int CD   = 8;
constexpr int HW   = 256;
constexpr int DHW  = CD * HW;        // 2048
constexpr int QSZ  = 2 * CC * DHW;   // 262144 floats per q/k/v buffer

// padded input layout for conv: [n 2][dp 10][g 8][row 18][col 18][cil 8] bf16
constexpr int PG    = 18 * 18;           // 324
constexpr int GPLN  = PG * 8;            // 2592 elems per (dp,g) plane
constexpr int PADSZ = 2 * 10 * 8 * GPLN; // 414720 elems per branch
// Wt layout: [branch][chunk 96][tapk 9][coh 2][pg 64][ci8] bf16, granule
// pg = (2*co + ks) ^ (co & 7)  (bank-floor swizzle, same XOR on read side).
constexpr int WTSZ  = 27 * 512 * 64;     // 884736 elems per branch
constexpr float LOG2E = 1.44269504088896f;

typedef __attribute__((ext_vector_type(8))) short bf16x8;
typedef __attribute__((ext_vector_type(4))) float f32x4;
typedef __attribute__((ext_vector_type(16))) float f32x16;

typedef unsigned int u32_g __attribute__((address_space(1)));
typedef unsigned int u32_l __attribute__((address_space(3)));

__device__ inline unsigned short f2bf(float f) {
    unsigned u = __float_as_uint(f);
    return (unsigned short)((u + 0x7fffu + ((u >> 16) & 1u)) >> 16);
}
}

// ---------------------------------------------------------------------------
// prep_small: [0,192) Wqkv bf16 stack | [192,597) zero padded P/D buffers.
// (Pads must be complete before att writes interiors — two launches later.)
// ---------------------------------------------------------------------------
__global__ __launch_bounds__(256) void prep_small_kernel(
    const float* __restrict__ Wq, const float* __restrict__ Wk,
    const float* __restrict__ Wv, unsigned short* __restrict__ Wqkv,
    uint4* __restrict__ pads)
{
    int bid = blockIdx.x;
    int t = threadIdx.x;
    if (bid < 192) {
        int co = bid;                 // 0..191
        const float* W = co < 64 ? Wq : co < 128 ? Wk : Wv;
        int c = co & 63;
        for (int ci = t; ci < 512; ci += 256)
            Wqkv[(size_t)co * 512 + ci] = f2bf(W[(size_t)c * 512 + ci]);
    } else {
        pads[(bid - 192) * 256 + t] = make_uint4(0, 0, 0, 0);
    }
}

// ---------------------------------------------------------------------------
// fused transpose + MFMA GEMM for q/k/v (+BN+ReLU). (R10 exact)
// ---------------------------------------------------------------------------
__global__ __launch_bounds__(256) void qkv_gemm_kernel(
    const float* __restrict__ x, const unsigned short* __restrict__ Wqkv,
    const float* __restrict__ bq, const float* __restrict__ gq,
    const float* __restrict__ btq, const float* __restrict__ mq,
    const float* __restrict__ vq,
    const float* __restrict__ bk, const float* __restrict__ gk,
    const float* __restrict__ btk, const float* __restrict__ mk,
    const float* __restrict__ vk,
    const float* __restrict__ bv, const float* __restrict__ gv,
    const float* __restrict__ btv, const float* __restrict__ mv,
    const float* __restrict__ vv,
    float* __restrict__ outq, float* __restrict__ outk, float* __restrict__ outv)
{
    int bid = blockIdx.x;
    int n = bid >> 7, p0 = (bid & 127) * 16;

    __shared__ __align__(16) unsigned short xs[16 * 512];   // 16 KB
    int t = threadIdx.x;

    const float* xb = x + ((size_t)n * C_IN) * DHW + p0;
#pragma unroll
    for (int pass = 0; pass < 8; ++pass) {
        int idx = pass * 256 + t;          // 0..2047
        int ci = idx >> 2, pq = idx & 3;
        float4 v4 = *reinterpret_cast<const float4*>(xb + (size_t)ci * DHW + pq * 4);
        float arr[4] = {v4.x, v4.y, v4.z, v4.w};
#pragma unroll
        for (int u = 0; u < 4; ++u) {
            int pos = pq * 4 + u;
            int boff = pos * 1024 + ((ci * 2) ^ ((pos & 7) << 4));
            *reinterpret_cast<unsigned short*>(
                reinterpret_cast<char*>(xs) + boff) = f2bf(arr[u]);
        }
    }
    __syncthreads();

    int wid = t >> 6, lane = t & 63;
    int l15 = lane & 15, l4 = lane >> 4;
    int mh = wid * 3;
    int pos = l15;

    bf16x8 bfr[16];
    const char* xsb = reinterpret_cast<const char*>(xs) + pos * 1024;
    int swz = (pos & 7) << 4;
#pragma unroll
    for (int kk = 0; kk < 16; ++kk)
        bfr[kk] = *reinterpret_cast<const bf16x8*>(xsb + ((kk * 64 + l4 * 16) ^ swz));

    f32x4 acc[3];
#pragma unroll
    for (int i = 0; i < 3; ++i) acc[i] = (f32x4){0.f, 0.f, 0.f, 0.f};

#pragma unroll
    for (int i = 0; i < 3; ++i) {
        const unsigned short* wrow =
            Wqkv + ((size_t)(mh + i) * 16 + l15) * 512 + l4 * 8;
#pragma unroll
        for (int kk = 0; kk < 16; ++kk) {
            bf16x8 af = *reinterpret_cast<const bf16x8*>(wrow + kk * 32);
            acc[i] = __builtin_amdgcn_mfma_f32_16x16x32_bf16(af, bfr[kk], acc[i], 0, 0, 0);
        }
    }

#pragma unroll
    for (int i = 0; i < 3; ++i) {
        int mf = mh + i;
        int br = mf >> 2;
        const float* bb  = br == 0 ? bq  : br == 1 ? bk  : bv;
        const float* gg  = br == 0 ? gq  : br == 1 ? gk  : gv;
        const float* bt  = br == 0 ? btq : br == 1 ? btk : btv;
        const float* mm  = br == 0 ? mq  : br == 1 ? mk  : mv;
        const float* vvp = br == 0 ? vq  : br == 1 ? vk  : vv;
        float*       op  = br == 0 ? outq : br == 1 ? outk : outv;
        int cb = (mf & 3) * 16 + l4 * 4;
#pragma unroll
        for (int r = 0; r < 4; ++r) {
            int c = cb + r;
            float s = gg[c] * rsqrtf(vvp[c] + EPSBN);
            float val = (acc[i][r] + bb[c] - mm[c]) * s + bt[c];
            op[((size_t)(n * CC + c)) * DHW + p0 + pos] = fmaxf(val, 0.f);
        }
    }
}

// ---------------------------------------------------------------------------
// att + conv-prep (merged grid — write-disjoint tail):
//   [0,1024)     spatial patt (float4 LDS reads, exp2 pre-scale)
//   [1024,1152)  temporal datt
//   [1152,1344)  Wt relayout, DEST-COALESCED (192 chunk-units, uint4 stores)
//   [1344,1348)  BN coefficient precompute
// ---------------------------------------------------------------------------
__global__ __launch_bounds__(256) void att_kernel(
    const float* __restrict__ q, const float* __restrict__ k,
    const float* __restrict__ v,
    const float* __restrict__ Ws, const float* __restrict__ Wd,
    const float* __restrict__ bs, const float* __restrict__ gs,
    const float* __restrict__ bts, const float* __restrict__ ms,
    const float* __restrict__ vs,
    const float* __restrict__ bd, const float* __restrict__ gd,
    const float* __restrict__ btd, const float* __restrict__ md,
    const float* __restrict__ vd,
    unsigned short* __restrict__ Pp, unsigned short* __restrict__ Dp,
    unsigned short* __restrict__ Wt, float2* __restrict__ BNc)
{
    __shared__ __align__(16) float sk[256], sq2[256], sw[256];
    __shared__ float red[4];
    int t = threadIdx.x;
    int bid = blockIdx.x;

    if (bid < 1024) {
        // ---- spatial attention over HW=256 for slice (n,c,d) ----
        int n = bid >> 9, c = (bid >> 3) & 63, d = bid & 7;
        size_t base = (size_t)bid * HW;
        float kt = k[base + t];
        float qt = q[base + t];
        float vt = v[base + t];
        float qt2 = qt * LOG2E;
        sk[t]  = kt;
        sq2[t] = qt2;

        float m = kt;
#pragma unroll
        for (int off = 32; off >= 1; off >>= 1)
            m = fmaxf(m, __shfl_xor(m, off));
        if ((t & 63) == 0) red[t >> 6] = m;
        __syncthreads();
        float kmax = fmaxf(fmaxf(red[0], red[1]), fmaxf(red[2], red[3]));

        float qkm2 = qt2 * kmax;
        float d0 = 0.f, d1 = 0.f, d2 = 0.f, d3 = 0.f;
        const float4* sk4 = reinterpret_cast<const float4*>(sk);
#pragma unroll 8
        for (int j = 0; j < 64; ++j) {
            float4 kk = sk4[j];
            d0 += __builtin_amdgcn_exp2f(fmaf(qt2, kk.x, -qkm2));
            d1 += __builtin_amdgcn_exp2f(fmaf(qt2, kk.y, -qkm2));
            d2 += __builtin_amdgcn_exp2f(fmaf(qt2, kk.z, -qkm2));
            d3 += __builtin_amdgcn_exp2f(fmaf(qt2, kk.w, -qkm2));
        }
        float den = (d0 + d1) + (d2 + d3);
        sw[t] = vt / den;
        __syncthreads();

        float kjm = kt - kmax;
        float o0 = 0.f, o1 = 0.f, o2 = 0.f, o3 = 0.f;
        const float4* sw4 = reinterpret_cast<const float4*>(sw);
        const float4* sq4 = reinterpret_cast<const float4*>(sq2);
#pragma unroll 8
        for (int i = 0; i < 64; ++i) {
            float4 ww = sw4[i];
            float4 qq = sq4[i];
            o0 += ww.x * __builtin_amdgcn_exp2f(qq.x * kjm);
            o1 += ww.y * __builtin_amdgcn_exp2f(qq.y * kjm);
            o2 += ww.z * __builtin_amdgcn_exp2f(qq.z * kjm);
            o3 += ww.w * __builtin_amdgcn_exp2f(qq.w * kjm);
        }
        float o = (o0 + o1) + (o2 + o3);

        int h = t >> 4, w = t & 15;
        size_t dst = ((((size_t)(n * 10 + d + 1) * 8 + (c >> 3)) * PG)
                      + (h + 1) * 18 + (w + 1)) * 8 + (c & 7);
        Pp[dst] = f2bf(o);
    } else if (bid < 1152) {
        // ---- temporal attention over D=8 per (n,c,h,w) ----
        int g = (bid - 1024) * 256 + t;
        int nc = g >> 8, hw = g & 255;
        int n = nc >> 6, c = nc & 63;
        size_t base = (size_t)nc * DHW + hw;

        float qv[8], kv[8], vv_[8];
#pragma unroll
        for (int d = 0; d < 8; ++d) {
            qv[d]  = q[base + d * HW];
            kv[d]  = k[base + d * HW];
            vv_[d] = v[base + d * HW];
        }
        float kmax = 0.f;
#pragma unroll
        for (int d = 0; d < 8; ++d) kmax = fmaxf(kmax, kv[d]);

        float wgt[8];
#pragma unroll
        for (int i = 0; i < 8; ++i) {
            float den = 0.f, qkm = qv[i] * kmax;
#pragma unroll
            for (int j = 0; j < 8; ++j)
                den += __expf(fmaf(qv[i], kv[j], -qkm));
            wgt[i] = vv_[i] / den;
        }
        int h = hw >> 4, w = hw & 15;
#pragma unroll
        for (int j = 0; j < 8; ++j) {
            float o = 0.f, kjm = kv[j] - kmax;
#pragma unroll
            for (int i = 0; i < 8; ++i)
                o += wgt[i] * __expf(qv[i] * kjm);
            size_t dst = ((((size_t)(n * 10 + j + 1) * 8 + (c >> 3)) * PG)
                          + (h + 1) * 18 + (w + 1)) * 8 + (c & 7);
            Dp[dst] = f2bf(o);
        }
    } else if (bid < 1344) {
        // ---- Wt relayout: destination-coalesced (inverse mapping) ----
        int u = bid - 1152;            // 0..191
        int b = u / 96, chunk = u - b * 96;
        const float* W = b ? Wd : Ws;
        int cig = chunk & 1;
        int kd  = (chunk >> 1) % 3;
        int hc  = chunk / 6;
        int half = hc & 1, cog = hc >> 1;
        unsigned short* o = Wt + (size_t)b * WTSZ + (size_t)chunk * 9216;
        int cibase0 = half * 32 + cig * 16;
#pragma unroll
        for (int it = 0; it < 5; ++it) {
            int q4 = it * 256 + t;         // uint4 index in chunk [0,1152)
            if (q4 < 1152) {
                int idx = q4 * 8;
                int tapk = idx >> 10;
                int rem  = idx & 1023;
                int hi   = rem >> 9;
                int pg   = (rem >> 3) & 63;
                // invert pg = (2r+ks) ^ (r&7)
                int r2 = (pg >> 3) & 1;
                int r1 = ((pg >> 2) & 1) ^ r2;
                int r0 = ((pg >> 1) & 1) ^ r1;
                int ks = (pg & 1) ^ r0;
                int r  = ((pg >> 3) << 2) | (r1 << 1) | r0;
                int co = cog * 64 + hi * 32 + r;
                int tap = kd * 9 + tapk;
                const float* src = W + (size_t)co * 1728
                                     + (size_t)(cibase0 + ks * 8) * 27 + tap;
                unsigned short v8[8];
#pragma unroll
                for (int cin = 0; cin < 8; ++cin)
                    v8[cin] = f2bf(src[cin * 27]);
                *reinterpret_cast<uint4*>(o + idx) =
                    *reinterpret_cast<const uint4*>(v8);
            }
        }
    } else {
        // ---- BN coefficients ----
        int gid = (bid - 1344) * 256 + t;     // 0..1023
        if (gid < 1024) {
            int br = gid >> 9, co = gid & 511;
            float s, o;
            if (br == 0) {
                s = gs[co] * rsqrtf(vs[co] + EPSBN);
                o = (bs[co] - ms[co]) * s + bts[co];
            } else {
                s = gd[co] * rsqrtf(vd[co] + EPSBN);
                o = (bd[co] - md[co]) * s + btd[co];
            }
            BNc[gid] = make_float2(s, o);
        }
    }
}

// ---------------------------------------------------------------------------
// fused dual-branch conv, 32x32x16 MFMA — R10 bulk-stage structure +
// counted-vmcnt weight pipeline (T4):
//   barrier_A -> DMAW(c+1) [9 loads/wave] -> s_waitcnt vmcnt(9) (chunk c
//   landed; c+1 stays IN FLIGHT) -> barrier_B -> sched_barrier -> COMPUTE(c).
// ISTAGE(1)'s 18 loads/wave (issued after COMPUTE(5)+barrier) are proven
// complete by step 6's vmcnt(9) (issue-order arithmetic per wave).
// ---------------------------------------------------------------------------
__global__ __launch_bounds__(256, 1) void conv_fused_kernel(
    const unsigned short* __restrict__ Pp, const unsigned short* __restrict__ Dp,
    const unsigned short* __restrict__ Wt,
    const float2* __restrict__ BNc,
    const float* __restrict__ x, const float* __restrict__ gama,
    float* __restrict__ out)
{
    int bid = blockIdx.x;
    int cog = bid & 7;             // == XCD (round-robin) -> weights L2-local
    int pgb = (bid >> 3) & 1;
    int sl  = bid >> 4;
    int n = sl >> 3, d = sl & 7;

    __shared__ __align__(16) unsigned short lds_in[24 * 1536];    // 73728 B
    __shared__ __align__(16) unsigned short lds_w[2 * 18432];     // 73728 B

    int t = threadIdx.x;
    int wid = t >> 6, lane = t & 63;
    int ph = wid & 1, br = wid >> 1;
    int col  = lane & 31;
    int wcol = lane & 15;
    int hl   = (lane >> 4) & 1;
    int ks   = lane >> 5;
    int gA   = ((col * 2 + ks) ^ (col & 7)) * 8;  // swizzled A granule offset

    f32x16 acc[2][2];
#pragma unroll
    for (int m = 0; m < 2; ++m)
#pragma unroll
        for (int p = 0; p < 2; ++p)
#pragma unroll
            for (int r = 0; r < 16; ++r)
                acc[m][p][r] = 0.f;

#define ISTAGE(hf_) do {                                                      \
    _Pragma("unroll")                                                         \
    for (int pc = 0; pc < 24; ++pc) {                                         \
        const unsigned short* sb = ((pc >= 12) ? Dp : Pp)                     \
            + ((size_t)((n * 10 + d + ((pc % 12) >> 2)) * 8 + (hf_) * 4       \
                        + ((pc % 12) & 3))) * GPLN + pgb * 1152;              \
        _Pragma("unroll")                                                     \
        for (int j = 0; j < 3; ++j) {                                         \
            if (((pc * 3 + j) & 3) == wid)                                    \
                __builtin_amdgcn_global_load_lds(                             \
                    (const u32_g*)(sb + j * 512 + lane * 8),                  \
                    (u32_l*)(lds_in + pc * 1536 + j * 512), 16, 0, 0);        \
        }                                                                     \
    }                                                                         \
} while (0)

#define DMAW(c_) do {                                                         \
    const int ch_ = (((cog * 2 + ((c_) / 6)) * 3 + (((c_) % 6) >> 1)) * 2     \
                     + ((c_) & 1)) * 9216;                                    \
    _Pragma("unroll")                                                         \
    for (int j = 0; j < 9; ++j) {                                             \
        int base = j * 2048 + wid * 512;                                      \
        const unsigned short* s0 = (base < 9216)                              \
            ? (Wt + ch_ + base)                                               \
            : (Wt + WTSZ + ch_ + (base - 9216));                              \
        __builtin_amdgcn_global_load_lds(                                     \
            (const u32_g*)(s0 + lane * 8),                                    \
            (u32_l*)(lds_w + ((c_) & 1) * 18432 + base), 16, 0, 0);           \
    }                                                                         \
} while (0)

#define COMPUTE(c_) do {                                                      \
    const int kd_ = ((c_) % 6) >> 1, cig_ = (c_) & 1;                         \
    const unsigned short* wb_ = lds_w + ((c_) & 1) * 18432 + br * 9216;       \
    const unsigned short* bp_ = lds_in + br * (12 * 1536)                     \
                                + (kd_ * 4 + cig_ * 2 + ks) * 1536;           \
    _Pragma("unroll")                                                         \
    for (int tapk = 0; tapk < 9; ++tapk) {                                    \
        const int kh_ = tapk / 3, kw_ = tapk % 3;                             \
        bf16x8 a0 = *(const bf16x8*)(wb_ + tapk * 1024 + gA);                 \
        bf16x8 a1 = *(const bf16x8*)(wb_ + tapk * 1024 + 512 + gA);           \
        bf16x8 b0 = *(const bf16x8*)(bp_ + ((ph * 4 + hl + kh_) * 18          \
                                     + wcol + kw_) * 8);                      \
        bf16x8 b1 = *(const bf16x8*)(bp_ + ((ph * 4 + 2 + hl + kh_) * 18      \
                                     + wcol + kw_) * 8);                      \
        acc[0][0] = __builtin_amdgcn_mfma_f32_32x32x16_bf16(a0, b0,           \
                        acc[0][0], 0, 0, 0);                                  \
        acc[0][1] = __builtin_amdgcn_mfma_f32_32x32x16_bf16(a0, b1,           \
                        acc[0][1], 0, 0, 0);                                  \
        acc[1][0] = __builtin_amdgcn_mfma_f32_32x32x16_bf16(a1, b0,           \
                        acc[1][0], 0, 0, 0);                                  \
        acc[1][1] = __builtin_amdgcn_mfma_f32_32x32x16_bf16(a1, b1,           \
                        acc[1][1], 0, 0, 0);                                  \
    }                                                                         \
} while (0)

    ISTAGE(0);
    DMAW(0);

#pragma unroll
    for (int c = 0; c < 12; ++c) {
        if (c > 0)
            __builtin_amdgcn_s_barrier();      // A: COMPUTE(c-1) done block-wide
        if (c < 11) {
            DMAW(c + 1);                       // 9 loads -> buffer (c+1)&1
            asm volatile("s_waitcnt vmcnt(9)" ::: "memory");   // chunk c ready
        } else {
            asm volatile("s_waitcnt vmcnt(0)" ::: "memory");
        }
        __builtin_amdgcn_s_barrier();          // B: ready block-wide
        __builtin_amdgcn_sched_barrier(0);
        COMPUTE(c);
        if (c == 5) {
            __builtin_amdgcn_s_barrier();      // half-0 input slab free
            ISTAGE(1);                         // proven done by step-6 vmcnt(9)
        }
    }

#undef ISTAGE
#undef DMAW
#undef COMPUTE

    // ---- fused epilogue: S-waves -> LDS, D-waves combine + store ----
    // (ep = lds_w buffer 0; COMPUTE(11) read buffer 1 -> disjoint)
    float gm = gama[0];
    float* ep = reinterpret_cast<float*>(lds_w);

    if (br == 0) {
#pragma unroll
        for (int m = 0; m < 2; ++m)
#pragma unroll
            for (int p = 0; p < 2; ++p)
#pragma unroll
                for (int r = 0; r < 16; ++r) {
                    int row = (r & 3) + 8 * (r >> 2) + 4 * ks;
                    float2 c2 = BNc[cog * 64 + m * 32 + row];
                    float v2 = fmaxf(acc[m][p][r] * c2.x + c2.y, 0.f);
                    ep[ph * 4096 + (m * 32 + row) * 64 + p * 32 + col] = v2;
                }
    }
    __syncthreads();
    if (br == 1) {
#pragma unroll
        for (int m = 0; m < 2; ++m)
#pragma unroll
            for (int p = 0; p < 2; ++p)
#pragma unroll
                for (int r = 0; r < 16; ++r) {
                    int row = (r & 3) + 8 * (r >> 2) + 4 * ks;
                    int co = cog * 64 + m * 32 + row;
                    float2 c2 = BNc[512 + co];
                    float rd = fmaxf(acc[m][p][r] * c2.x + c2.y, 0.f);
                    float rp = ep[ph * 4096 + (m * 32 + row) * 64 + p * 32 + col];
                    int pos = pgb * 128 + ph * 64 + p * 32 + col;
                    size_t oi = ((size_t)(n * 512 + co)) * 2048 + d * 256 + pos;
                    out[oi] = gm * (rp + rd) + x[oi];
                }
    }
}

// ---------------------------------------------------------------------------
extern "C" void kernel_launch(void* const* d_in, const int* in_sizes, int n_in,
                              void* d_out, int out_size, void* d_ws, size_t ws_size,
                              hipStream_t stream)
{
    const float* x    = (const float*)d_in[0];
    const float* gama = (const float*)d_in[1];
    const float* Wq  = (const float*)d_in[2];
    const float* bq  = (const float*)d_in[3];
    const float* gq  = (const float*)d_in[4];
    const float* btq = (const float*)d_in[5];
    const float* mq  = (const float*)d_in[6];
    const float* vq  = (const float*)d_in[7];
    const float* Wk  = (const float*)d_in[8];
    const float* bk  = (const float*)d_in[9];
    const float* gk  = (const float*)d_in[10];
    const float* btk = (const float*)d_in[11];
    const float* mk  = (const float*)d_in[12];
    const float* vk  = (const float*)d_in[13];
    const float* Wv  = (const float*)d_in[14];
    const float* bv  = (const float*)d_in[15];
    const float* gv  = (const float*)d_in[16];
    const float* btv = (const float*)d_in[17];
    const float* mv  = (const float*)d_in[18];
    const float* vv  = (const float*)d_in[19];
    const float* Ws  = (const float*)d_in[20];
    const float* bs  = (const float*)d_in[21];
    const float* gs  = (const float*)d_in[22];
    const float* bts = (const float*)d_in[23];
    const float* ms  = (const float*)d_in[24];
    const float* vs  = (const float*)d_in[25];
    const float* Wd  = (const float*)d_in[26];
    const float* bd  = (const float*)d_in[27];
    const float* gd  = (const float*)d_in[28];
    const float* btd = (const float*)d_in[29];
    const float* md  = (const float*)d_in[30];
    const float* vd  = (const float*)d_in[31];

    char* ws = (char*)d_ws;
    unsigned short* Pp   = (unsigned short*)ws;                 // 829440 B
    unsigned short* Dp   = Pp + PADSZ;                          // 829440 B
    unsigned short* Wt   = Dp + PADSZ;                          // 3538944 B
    unsigned short* Wqkv = Wt + 2 * WTSZ;                       // 196608 B
    float* q = (float*)(ws + 5394432);
    float* k = q + QSZ;
    float* v = k + QSZ;
    float2* BNc = (float2*)(ws + 5394432 + 3 * 1048576);        // 8192 B

    prep_small_kernel<<<597, 256, 0, stream>>>(Wq, Wk, Wv, Wqkv, (uint4*)Pp);

    qkv_gemm_kernel<<<256, 256, 0, stream>>>(
        x, Wqkv,
        bq, gq, btq, mq, vq,
        bk, gk, btk, mk, vk,
        bv, gv, btv, mv, vv,
        q, k, v);

    att_kernel<<<1348, 256, 0, stream>>>(
        q, k, v,
        Ws, Wd,
        bs, gs, bts, ms, vs,
        bd, gd, btd, md, vd,
        Pp, Dp, Wt, BNc);

    conv_fused_kernel<<<256, 256, 0, stream>>>(
        Pp, Dp, Wt, BNc,
        x, gama, (float*)d_out);
}